// Round 8
// baseline (263.501 us; speedup 1.0000x reference)
//
#include <hip/hip_runtime.h>

// TCM_77464030151162: x(N,128)@w1+b1 -> split 64/64 -> two gathered 3^3 sparse
// convs (27 offsets, 64x64 each, ReLU) -> +2*conv_x residual -> concat@w2+b2 -> +x.
// fp32 wire, bf16 MFMA compute.
// R8: conv = R4-exact (proven 47.5us). k_prep rebuilt with LDS transpose (R7's
// scattered 2B writes were ~30-40us). GEMMs pipelined: 2 chunks/block, next
// chunk's A-loads issued before current chunk's compute; weights staged once.
// y split into yc/yt (N x 64 each) for compact conv gathers.

#define N_PTS 100000
#define NBLK128 782  // ceil(100000/128) - conv blocks; also gemm grid (2x64-row chunks)

typedef __attribute__((ext_vector_type(8))) short frag_ab; // 8 bf16 (4 VGPRs)
typedef __attribute__((ext_vector_type(4))) float f32x4;   // MFMA 16x16 C/D
#define ZFRAG frag_ab{0, 0, 0, 0, 0, 0, 0, 0}

__device__ __forceinline__ unsigned short f2bf(float f) {
  union { float f; unsigned int i; } v; v.f = f;
  unsigned int r = v.i + 0x7fffu + ((v.i >> 16) & 1u); // RNE
  return (unsigned short)(r >> 16);
}
__device__ __forceinline__ float bf2f(unsigned short u) {
  union { unsigned int i; float f; } v; v.i = ((unsigned int)u) << 16; return v.f;
}

// async global->LDS, 16B per lane. LDS dest = wave-uniform base + lane*16 (m104).
__device__ __forceinline__ void gload_lds16(const unsigned short* g, unsigned short* l) {
  __builtin_amdgcn_global_load_lds(
      (const __attribute__((address_space(1))) unsigned int*)g,
      (__attribute__((address_space(3))) unsigned int*)(unsigned int)(size_t)l,
      16, 0, 0);
}

// ---- weight convert+transpose+swizzle via LDS (coalesced both directions) ----
// w1T/w2T: (d,c); 16B chunk (c>>3) stored at chunk^(d&15).
// rw1T/rw2T: (k,d,c); 16B chunk (c>>3) stored at chunk^(d&7).
// Blocks 0..15: w1/w2, 16 d-rows each. Blocks 16..42: rw1+rw2, one k each.
__global__ __launch_bounds__(256) void k_prep(
    const float* __restrict__ w1, const float* __restrict__ w2,
    const float* __restrict__ rw1, const float* __restrict__ rw2,
    unsigned short* __restrict__ w1T, unsigned short* __restrict__ w2T,
    unsigned short* __restrict__ rw1T, unsigned short* __restrict__ rw2T) {
  __shared__ unsigned short L[8320];
  const int tid = threadIdx.x, bid = blockIdx.x;
  if (bid < 16) {
    const float* src = (bid < 8) ? w1 : w2;
    unsigned short* dst = (bid < 8) ? w1T : w2T;
    const int seg = bid & 7; // d rows [seg*16, seg*16+16)
#pragma unroll
    for (int i = 0; i < 8; ++i) {
      int idx = i * 256 + tid; // 0..2047
      int c = idx >> 4, dl = idx & 15;
      L[c * 17 + dl] = f2bf(src[c * 128 + seg * 16 + dl]);
    }
    __syncthreads();
    const int dl = tid >> 4, j = tid & 15;
    const int d = seg * 16 + dl;
    frag_ab v;
#pragma unroll
    for (int i = 0; i < 8; ++i) v[i] = (short)L[(8 * j + i) * 17 + dl];
    *(frag_ab*)(dst + d * 128 + ((j ^ (d & 15)) << 3)) = v;
  } else {
    const int k = bid - 16;
#pragma unroll
    for (int i = 0; i < 16; ++i) {
      int idx = i * 256 + tid; // 0..4095, c=idx>>6, d=idx&63
      int c = idx >> 6, d = idx & 63;
      L[c * 65 + d] = f2bf(rw1[k * 4096 + idx]);
      L[4160 + c * 65 + d] = f2bf(rw2[k * 4096 + idx]);
    }
    __syncthreads();
#pragma unroll
    for (int h = 0; h < 2; ++h) {
      int cid = h * 256 + tid; // 0..511
      int d = cid >> 3, j = cid & 7;
      frag_ab v1, v2;
#pragma unroll
      for (int i = 0; i < 8; ++i) {
        v1[i] = (short)L[(8 * j + i) * 65 + d];
        v2[i] = (short)L[4160 + (8 * j + i) * 65 + d];
      }
      int pos = k * 4096 + d * 64 + ((j ^ (d & 7)) << 3);
      *(frag_ab*)(rw1T + pos) = v1;
      *(frag_ab*)(rw2T + pos) = v2;
    }
  }
}

// ---- y = bf16(x) @ w1 + b1, split-store to yc/yt ----
// grid 782, 2 chunks of 64 rows per block; wave = 16 rows; pipelined A-loads.
__global__ __launch_bounds__(256) void k_gemm_in(
    const float* __restrict__ x, const unsigned short* __restrict__ w1T,
    const float* __restrict__ b1, unsigned short* __restrict__ yc,
    unsigned short* __restrict__ yt) {
  __shared__ unsigned short sw[16384]; // 32KB
  const int tid = threadIdx.x, lane = tid & 63, w = tid >> 6;
  const int m16 = lane & 15, q = lane >> 4;
#pragma unroll
  for (int r = 0; r < 8; ++r) {
    const int off = (r * 256 + tid) * 8;
    gload_lds16(w1T + off, &sw[off]);
  }
  const int ci0 = blockIdx.x * 2;
  const int rb0 = ci0 * 64 + w * 16;
  const int rc0 = (rb0 + m16) < N_PTS ? (rb0 + m16) : N_PTS - 1;
  float4 xA[4][2];
#pragma unroll
  for (int kk = 0; kk < 4; ++kk) {
    const float* xp = x + (size_t)rc0 * 128 + kk * 32 + q * 8;
    xA[kk][0] = *(const float4*)xp;
    xA[kk][1] = *(const float4*)(xp + 4);
  }
  __syncthreads();

  // prefetch chunk 1
  const int rb1 = (ci0 + 1) * 64 + w * 16;
  const int rc1 = (rb1 + m16) < N_PTS ? (rb1 + m16) : N_PTS - 1;
  float4 xB[4][2];
#pragma unroll
  for (int kk = 0; kk < 4; ++kk) {
    const float* xp = x + (size_t)rc1 * 128 + kk * 32 + q * 8;
    xB[kk][0] = *(const float4*)xp;
    xB[kk][1] = *(const float4*)(xp + 4);
  }

  // compute + store chunk 0
  {
    f32x4 acc[8] = {};
#pragma unroll
    for (int kk = 0; kk < 4; ++kk) {
      float4 f0 = xA[kk][0], f1 = xA[kk][1];
      frag_ab a;
      a[0] = (short)f2bf(f0.x); a[1] = (short)f2bf(f0.y);
      a[2] = (short)f2bf(f0.z); a[3] = (short)f2bf(f0.w);
      a[4] = (short)f2bf(f1.x); a[5] = (short)f2bf(f1.y);
      a[6] = (short)f2bf(f1.z); a[7] = (short)f2bf(f1.w);
#pragma unroll
      for (int ct = 0; ct < 8; ++ct) {
        const int d = ct * 16 + m16;
        const int phys = ((kk << 2) | q) ^ m16;
        frag_ab bf = *(const frag_ab*)(&sw[d * 128 + phys * 8]);
        acc[ct] = __builtin_amdgcn_mfma_f32_16x16x32_bf16(a, bf, acc[ct], 0, 0, 0);
      }
    }
#pragma unroll
    for (int ct = 0; ct < 8; ++ct) {
      const int col = ct * 16 + m16;
      const float bias = b1[col];
#pragma unroll
      for (int j = 0; j < 4; ++j) {
        int r = rb0 + q * 4 + j;
        if (r < N_PTS) {
          unsigned short val = f2bf(acc[ct][j] + bias);
          if (ct < 4) yc[(size_t)r * 64 + col] = val;
          else        yt[(size_t)r * 64 + (col - 64)] = val;
        }
      }
    }
  }
  // compute + store chunk 1
  {
    f32x4 acc[8] = {};
#pragma unroll
    for (int kk = 0; kk < 4; ++kk) {
      float4 f0 = xB[kk][0], f1 = xB[kk][1];
      frag_ab a;
      a[0] = (short)f2bf(f0.x); a[1] = (short)f2bf(f0.y);
      a[2] = (short)f2bf(f0.z); a[3] = (short)f2bf(f0.w);
      a[4] = (short)f2bf(f1.x); a[5] = (short)f2bf(f1.y);
      a[6] = (short)f2bf(f1.z); a[7] = (short)f2bf(f1.w);
#pragma unroll
      for (int ct = 0; ct < 8; ++ct) {
        const int d = ct * 16 + m16;
        const int phys = ((kk << 2) | q) ^ m16;
        frag_ab bf = *(const frag_ab*)(&sw[d * 128 + phys * 8]);
        acc[ct] = __builtin_amdgcn_mfma_f32_16x16x32_bf16(a, bf, acc[ct], 0, 0, 0);
      }
    }
#pragma unroll
    for (int ct = 0; ct < 8; ++ct) {
      const int col = ct * 16 + m16;
      const float bias = b1[col];
#pragma unroll
      for (int j = 0; j < 4; ++j) {
        int r = rb1 + q * 4 + j;
        if (r < N_PTS) {
          unsigned short val = f2bf(acc[ct][j] + bias);
          if (ct < 4) yc[(size_t)r * 64 + col] = val;
          else        yt[(size_t)r * 64 + (col - 64)] = val;
        }
      }
    }
  }
}

// ---- gathered sparse conv (R4-exact): per-k LDS staging, double-buffered ----
// feat rows are compact 64ch (fstride=64). FUSE: += 2*res[n,:] (res stride 64).
template <bool FUSE>
__global__ __launch_bounds__(256) void k_conv(
    const unsigned short* __restrict__ feat, const int fstride,
    const int* __restrict__ nbr,
    const unsigned short* __restrict__ rwT, const float* __restrict__ rb,
    const unsigned short* __restrict__ res, unsigned short* __restrict__ out) {
  __shared__ unsigned short sw[2][4096]; // 2 x 8KB ping-pong
  const int tid = threadIdx.x, lane = tid & 63, w = tid >> 6;
  const int m16 = lane & 15, q = lane >> 4;
  const int rowbase = blockIdx.x * 128 + w * 32;
  const int p0 = rowbase + m16, p1 = p0 + 16;
  const bool v0 = p0 < N_PTS, v1 = p1 < N_PTS;
  const int s0 = w * 1024 + lane * 8;
  const int s1 = s0 + 512;

  int i0r[2], i1r[2];
  i0r[0] = v0 ? nbr[p0] : -1;
  i1r[0] = v1 ? nbr[p1] : -1;
  i0r[1] = v0 ? nbr[N_PTS + p0] : -1;
  i1r[1] = v1 ? nbr[N_PTS + p1] : -1;

  frag_ab A[2][2][2]; // [ring][rt][kk]
#pragma unroll
  for (int a = 0; a < 2; ++a)
#pragma unroll
    for (int b = 0; b < 2; ++b)
#pragma unroll
      for (int c = 0; c < 2; ++c) A[a][b][c] = ZFRAG;

  {
    gload_lds16(rwT + s0, &sw[0][s0]);
    gload_lds16(rwT + s1, &sw[0][s1]);
    if (i0r[0] >= 0) {
      const unsigned short* fp = feat + (size_t)i0r[0] * fstride + q * 8;
      A[0][0][0] = *(const frag_ab*)fp; A[0][0][1] = *(const frag_ab*)(fp + 32);
    }
    if (i1r[0] >= 0) {
      const unsigned short* fp = feat + (size_t)i1r[0] * fstride + q * 8;
      A[0][1][0] = *(const frag_ab*)fp; A[0][1][1] = *(const frag_ab*)(fp + 32);
    }
  }
  __syncthreads();

  f32x4 acc[2][4] = {};
#pragma unroll
  for (int k = 0; k < 27; ++k) {
    const int b = k & 1;
    if (k + 1 < 27) {
      const unsigned short* src = rwT + ((k + 1) << 12);
      gload_lds16(src + s0, &sw[b ^ 1][s0]);
      gload_lds16(src + s1, &sw[b ^ 1][s1]);
      const int n = (k + 1) & 1;
      int j0 = i0r[n], j1 = i1r[n];
      A[n][0][0] = ZFRAG; A[n][0][1] = ZFRAG; A[n][1][0] = ZFRAG; A[n][1][1] = ZFRAG;
      if (j0 >= 0) {
        const unsigned short* fp = feat + (size_t)j0 * fstride + q * 8;
        A[n][0][0] = *(const frag_ab*)fp; A[n][0][1] = *(const frag_ab*)(fp + 32);
      }
      if (j1 >= 0) {
        const unsigned short* fp = feat + (size_t)j1 * fstride + q * 8;
        A[n][1][0] = *(const frag_ab*)fp; A[n][1][1] = *(const frag_ab*)(fp + 32);
      }
    }
    if (k + 2 < 27) {
      i0r[k & 1] = v0 ? nbr[(k + 2) * N_PTS + p0] : -1;
      i1r[k & 1] = v1 ? nbr[(k + 2) * N_PTS + p1] : -1;
    }
#pragma unroll
    for (int kk = 0; kk < 2; ++kk)
#pragma unroll
      for (int ct = 0; ct < 4; ++ct) {
        const int d = ct * 16 + m16;
        const int phys = ((kk << 2) | q) ^ (m16 & 7);
        frag_ab bf = *(const frag_ab*)(&sw[b][d * 64 + phys * 8]);
        acc[0][ct] = __builtin_amdgcn_mfma_f32_16x16x32_bf16(A[b][0][kk], bf, acc[0][ct], 0, 0, 0);
        acc[1][ct] = __builtin_amdgcn_mfma_f32_16x16x32_bf16(A[b][1][kk], bf, acc[1][ct], 0, 0, 0);
      }
    __syncthreads();
  }

#pragma unroll
  for (int ct = 0; ct < 4; ++ct) {
    const int col = ct * 16 + m16;
    const float bias = rb[col];
#pragma unroll
    for (int rt = 0; rt < 2; ++rt)
#pragma unroll
      for (int j = 0; j < 4; ++j) {
        const int r = rowbase + rt * 16 + q * 4 + j;
        if (r < N_PTS) {
          float v = acc[rt][ct][j] + bias;
          v = v > 0.f ? v : 0.f;
          if constexpr (FUSE) v += 2.f * bf2f(res[(size_t)r * 64 + col]);
          out[(size_t)r * 64 + col] = f2bf(v);
        }
      }
  }
}

// ---- out = x + [z1 | yt] @ w2 + b2 ; grid 782, 2 chunks/block, pipelined ----
__global__ __launch_bounds__(256) void k_gemm_out(
    const float* __restrict__ x, const unsigned short* __restrict__ z1,
    const unsigned short* __restrict__ yt, const unsigned short* __restrict__ w2T,
    const float* __restrict__ b2, float* __restrict__ out) {
  __shared__ unsigned short sw[16384]; // 32KB
  const int tid = threadIdx.x, lane = tid & 63, w = tid >> 6;
  const int m16 = lane & 15, q = lane >> 4;
#pragma unroll
  for (int r = 0; r < 8; ++r) {
    const int off = (r * 256 + tid) * 8;
    gload_lds16(w2T + off, &sw[off]);
  }
  const int ci0 = blockIdx.x * 2;
  const int rb0 = ci0 * 64 + w * 16;
  const int rc0 = (rb0 + m16) < N_PTS ? (rb0 + m16) : N_PTS - 1;
  frag_ab aA[4];
#pragma unroll
  for (int kk = 0; kk < 4; ++kk) {
    const unsigned short* ap = (kk < 2)
        ? (z1 + (size_t)rc0 * 64 + kk * 32 + q * 8)
        : (yt + (size_t)rc0 * 64 + (kk - 2) * 32 + q * 8);
    aA[kk] = *(const frag_ab*)ap;
  }
  __syncthreads();

  const int rb1 = (ci0 + 1) * 64 + w * 16;
  const int rc1 = (rb1 + m16) < N_PTS ? (rb1 + m16) : N_PTS - 1;
  frag_ab aB[4];
#pragma unroll
  for (int kk = 0; kk < 4; ++kk) {
    const unsigned short* ap = (kk < 2)
        ? (z1 + (size_t)rc1 * 64 + kk * 32 + q * 8)
        : (yt + (size_t)rc1 * 64 + (kk - 2) * 32 + q * 8);
    aB[kk] = *(const frag_ab*)ap;
  }

  {
    f32x4 acc[8] = {};
#pragma unroll
    for (int kk = 0; kk < 4; ++kk)
#pragma unroll
      for (int ct = 0; ct < 8; ++ct) {
        const int d = ct * 16 + m16;
        const int phys = ((kk << 2) | q) ^ m16;
        frag_ab bf = *(const frag_ab*)(&sw[d * 128 + phys * 8]);
        acc[ct] = __builtin_amdgcn_mfma_f32_16x16x32_bf16(aA[kk], bf, acc[ct], 0, 0, 0);
      }
#pragma unroll
    for (int ct = 0; ct < 8; ++ct) {
      const int col = ct * 16 + m16;
      const float bias = b2[col];
#pragma unroll
      for (int j = 0; j < 4; ++j) {
        int r = rb0 + q * 4 + j;
        if (r < N_PTS) {
          size_t o = (size_t)r * 128 + col;
          out[o] = acc[ct][j] + bias + x[o];
        }
      }
    }
  }
  {
    f32x4 acc[8] = {};
#pragma unroll
    for (int kk = 0; kk < 4; ++kk)
#pragma unroll
      for (int ct = 0; ct < 8; ++ct) {
        const int d = ct * 16 + m16;
        const int phys = ((kk << 2) | q) ^ m16;
        frag_ab bf = *(const frag_ab*)(&sw[d * 128 + phys * 8]);
        acc[ct] = __builtin_amdgcn_mfma_f32_16x16x32_bf16(aB[kk], bf, acc[ct], 0, 0, 0);
      }
#pragma unroll
    for (int ct = 0; ct < 8; ++ct) {
      const int col = ct * 16 + m16;
      const float bias = b2[col];
#pragma unroll
      for (int j = 0; j < 4; ++j) {
        int r = rb1 + q * 4 + j;
        if (r < N_PTS) {
          size_t o = (size_t)r * 128 + col;
          out[o] = acc[ct][j] + bias + x[o];
        }
      }
    }
  }
}

extern "C" void kernel_launch(void* const* d_in, const int* in_sizes, int n_in,
                              void* d_out, int out_size, void* d_ws, size_t ws_size,
                              hipStream_t stream) {
  const float* x   = (const float*)d_in[0];
  const float* w1  = (const float*)d_in[1];
  const float* b1  = (const float*)d_in[2];
  const float* w2  = (const float*)d_in[3];
  const float* b2  = (const float*)d_in[4];
  const float* rw1 = (const float*)d_in[5];
  const float* rb1 = (const float*)d_in[6];
  const float* rw2 = (const float*)d_in[7];
  const float* rb2 = (const float*)d_in[8];
  const int* nbr = (const int*)d_in[9];
  float* out = (float*)d_out;

  char* ws = (char*)d_ws;
  unsigned short* w1T  = (unsigned short*)(ws);                       // 32 KB
  unsigned short* w2T  = (unsigned short*)(ws + 32768);               // 32 KB
  unsigned short* rw1T = (unsigned short*)(ws + 65536);               // 216 KB
  unsigned short* rw2T = (unsigned short*)(ws + 286720);              // 216 KB
  unsigned short* yc   = (unsigned short*)(ws + 507904);              // 12.8 MB
  unsigned short* yt   = (unsigned short*)(ws + 507904 + 12800000);   // 12.8 MB
  unsigned short* r1   = (unsigned short*)(ws + 507904 + 25600000);   // 12.8 MB
  unsigned short* z1   = (unsigned short*)(ws + 507904 + 38400000);   // 12.8 MB

  k_prep<<<43, 256, 0, stream>>>(w1, w2, rw1, rw2, w1T, w2T, rw1T, rw2T);
  k_gemm_in<<<NBLK128, 256, 0, stream>>>(x, w1T, b1, yc, yt);
  k_conv<false><<<NBLK128, 256, 0, stream>>>(yc, 64, nbr, rw1T, rb1, nullptr, r1);
  k_conv<true><<<NBLK128, 256, 0, stream>>>(r1, 64, nbr, rw2T, rb2, yc, z1);
  k_gemm_out<<<NBLK128, 256, 0, stream>>>(x, z1, yt, w2T, b2, out);
}